// Round 10
// baseline (275.864 us; speedup 1.0000x reference)
//
#include <hip/hip_runtime.h>
#include <hip/hip_bf16.h>
#include <math.h>

// Sizes (fixed by the problem)
#define BATCH 16
#define TLEN  512
#define HD    16     // per-direction hidden
#define HID   32     // 2*HD

typedef float v2f __attribute__((ext_vector_type(2)));
typedef unsigned u2v __attribute__((ext_vector_type(2)));

// Static device scratch — avoids any assumption about ws_size.
__device__ float g_outBT[BATCH * TLEN * HID];   // 1 MB
__device__ float g_preA [BATCH * TLEN * HID];   // 1 MB
__device__ float g_Ct   [BATCH * HID * TLEN];   // 1 MB
__device__ float g_un   [BATCH * TLEN];
__device__ float g_w2d  [BATCH * TLEN];
__device__ float g_accum[BATCH];                // zero-initialized, self-resetting
__device__ int   g_cnt  [BATCH];                // zero-initialized, self-resetting

__device__ __forceinline__ float sigm_(float x) {
    return 1.0f / (1.0f + __expf(-x));
}

__device__ __forceinline__ float ex2_(float x) {
#if __has_builtin(__builtin_amdgcn_exp2f)
    return __builtin_amdgcn_exp2f(x);     // raw v_exp_f32 (2^x)
#else
    return exp2f(x);
#endif
}
__device__ __forceinline__ float rcp_(float x) {
#if __has_builtin(__builtin_amdgcn_rcpf)
    return __builtin_amdgcn_rcpf(x);      // raw v_rcp_f32 — avoids IEEE div chain
#else
    return 1.0f / x;
#endif
}

// ---------------------------------------------------------------------------
// K1: bidirectional LSTM, round 16 — TWO independent chains per wave.
// Round-9 post-mortem: chain-depth surgery (+6 issue ops) REGRESSED 82->86;
// round-8 (issue cut) won 101->82. Mixed issue/latency regime. At 384
// cyc/step with ~100-135 cyc issue, ~250 cyc are dependency stalls that only
// INDEPENDENT work can fill — so merge the fwd and bwd chains of one batch
// into ONE wave (16 blocks). All cross-lane ops (DPP ror, permlane swaps)
// are per-register with identical lane topology for both chains, so the two
// chains interleave freely and their stalls overlap. Per-iteration wall =
// max(2x issue, chain latency) covering TWO steps.
// Discriminator: if neutral vs 82 us -> step was issue-bound (plateau).
// Step body = round-8 EXACT (known 81.9 us, absmax 0): 4-accum dot,
// permlane gather with select ladder, folded exp2 scales, scaled-c tanh.
// ---------------------------------------------------------------------------

// One LSTM step for one chain. HN/CC: state (lvalues). WH: 16-elem weight
// array (fully unrolled constant indices -> registers). PBV: x*wx+b base.
// Uses outer-scope mm/aa/gb0/gb1 (per-lane activation/role constants).
#define LSTM_STEP(HN, CC, WH, PBV, OUTV)                                        \
{                                                                               \
    const int r0i_ = __float_as_int(HN);                                        \
    float rot_[16];                                                             \
    rot_[0]  = HN;                                                              \
    rot_[1]  = __int_as_float(__builtin_amdgcn_mov_dpp(r0i_, 0x121, 0xF, 0xF, true)); \
    rot_[2]  = __int_as_float(__builtin_amdgcn_mov_dpp(r0i_, 0x122, 0xF, 0xF, true)); \
    rot_[3]  = __int_as_float(__builtin_amdgcn_mov_dpp(r0i_, 0x123, 0xF, 0xF, true)); \
    rot_[4]  = __int_as_float(__builtin_amdgcn_mov_dpp(r0i_, 0x124, 0xF, 0xF, true)); \
    rot_[5]  = __int_as_float(__builtin_amdgcn_mov_dpp(r0i_, 0x125, 0xF, 0xF, true)); \
    rot_[6]  = __int_as_float(__builtin_amdgcn_mov_dpp(r0i_, 0x126, 0xF, 0xF, true)); \
    rot_[7]  = __int_as_float(__builtin_amdgcn_mov_dpp(r0i_, 0x127, 0xF, 0xF, true)); \
    rot_[8]  = __int_as_float(__builtin_amdgcn_mov_dpp(r0i_, 0x128, 0xF, 0xF, true)); \
    rot_[9]  = __int_as_float(__builtin_amdgcn_mov_dpp(r0i_, 0x129, 0xF, 0xF, true)); \
    rot_[10] = __int_as_float(__builtin_amdgcn_mov_dpp(r0i_, 0x12A, 0xF, 0xF, true)); \
    rot_[11] = __int_as_float(__builtin_amdgcn_mov_dpp(r0i_, 0x12B, 0xF, 0xF, true)); \
    rot_[12] = __int_as_float(__builtin_amdgcn_mov_dpp(r0i_, 0x12C, 0xF, 0xF, true)); \
    rot_[13] = __int_as_float(__builtin_amdgcn_mov_dpp(r0i_, 0x12D, 0xF, 0xF, true)); \
    rot_[14] = __int_as_float(__builtin_amdgcn_mov_dpp(r0i_, 0x12E, 0xF, 0xF, true)); \
    rot_[15] = __int_as_float(__builtin_amdgcn_mov_dpp(r0i_, 0x12F, 0xF, 0xF, true)); \
    float a0_ = fmaf(rot_[0], WH[0], PBV);                                      \
    float a1_ = rot_[1] * WH[1];                                                \
    float a2_ = rot_[2] * WH[2];                                                \
    float a3_ = rot_[3] * WH[3];                                                \
    a0_ = fmaf(rot_[4],  WH[4],  a0_);                                          \
    a1_ = fmaf(rot_[5],  WH[5],  a1_);                                          \
    a2_ = fmaf(rot_[6],  WH[6],  a2_);                                          \
    a3_ = fmaf(rot_[7],  WH[7],  a3_);                                          \
    a0_ = fmaf(rot_[8],  WH[8],  a0_);                                          \
    a1_ = fmaf(rot_[9],  WH[9],  a1_);                                          \
    a2_ = fmaf(rot_[10], WH[10], a2_);                                          \
    a3_ = fmaf(rot_[11], WH[11], a3_);                                          \
    a0_ = fmaf(rot_[12], WH[12], a0_);                                          \
    a1_ = fmaf(rot_[13], WH[13], a1_);                                          \
    a2_ = fmaf(rot_[14], WH[14], a2_);                                          \
    a3_ = fmaf(rot_[15], WH[15], a3_);                                          \
    const float p_ = (a0_ + a1_) + (a2_ + a3_);                                 \
    const float e_   = ex2_(p_);                                                \
    const float iv_  = rcp_(e_ + 1.0f);                                         \
    const float act_ = fmaf(mm, iv_, aa);                                       \
    float x1_, x2_, x3_;                                                        \
    {                                                                           \
        const unsigned ai_ = (unsigned)__float_as_int(act_);                    \
        u2v q16_ = __builtin_amdgcn_permlane16_swap(ai_, ai_, false, false);    \
        x1_ = __int_as_float((int)(gb0 ? q16_[0] : q16_[1]));                   \
        u2v q32_ = __builtin_amdgcn_permlane32_swap(ai_, ai_, false, false);    \
        const unsigned x2i_ = gb1 ? q32_[0] : q32_[1];                          \
        x2_ = __int_as_float((int)x2i_);                                        \
        u2v q48_ = __builtin_amdgcn_permlane16_swap(x2i_, x2i_, false, false);  \
        x3_ = __int_as_float((int)(gb0 ? q48_[0] : q48_[1]));                   \
    }                                                                           \
    const float lo_i_ = gb0 ? x1_  : act_;                                      \
    const float hi_i_ = gb0 ? x3_  : x2_;                                       \
    const float ai2_  = gb1 ? hi_i_ : lo_i_;                                    \
    const float lo_f_ = gb0 ? act_ : x1_;                                       \
    const float hi_f_ = gb0 ? x2_  : x3_;                                       \
    const float af_   = gb1 ? hi_f_ : lo_f_;                                    \
    const float lo_g_ = gb0 ? x1_  : act_;                                      \
    const float hi_g_ = gb0 ? x3_  : x2_;                                       \
    const float ag_   = gb1 ? lo_g_ : hi_g_;                                    \
    const float lo_o_ = gb0 ? act_ : x1_;                                       \
    const float hi_o_ = gb0 ? x2_  : x3_;                                       \
    const float ao_   = gb1 ? lo_o_ : hi_o_;                                    \
    CC = fmaf(af_, CC, ai2_ * ag_);                                             \
    const float e2_   = ex2_(CC);                                               \
    const float inv2_ = rcp_(e2_ + 1.0f);                                       \
    const float z_    = fmaf(-2.0f, inv2_, 1.0f);                               \
    HN = ao_ * z_;                                                              \
    OUTV = HN;                                                                  \
}

__global__ __launch_bounds__(64, 1) void k1_lstm(
    const float* __restrict__ sent,   // [B,T]
    const float* __restrict__ h0,     // [2,B,16]
    const float* __restrict__ c0,     // [2,B,16]
    const float* __restrict__ Wih_f, const float* __restrict__ Whh_f, const float* __restrict__ b_f,
    const float* __restrict__ Wih_b, const float* __restrict__ Whh_b, const float* __restrict__ b_b)
{
    const int b = blockIdx.x;         // 0..15 — one batch per block, BOTH dirs
    const int r = threadIdx.x;        // gate row 0..63
    const int u = r & 15;             // unit
    const int g = r >> 4;             // 0=i,1=f,2=g,3=o

    const float L2E = 1.4426950408889634f;
    // fold the exp2 argument scale into this gate row's weights:
    //   sigm rows (i,f,o): p' = -log2e * p  -> sigm(p) = rcp(2^p' + 1)
    //   tanh row  (g):     p' = 2*log2e * p -> tanh(p) = 1 - 2*rcp(2^p' + 1)
    const bool  isg = (g == 2);
    const float sc  = isg ? (2.0f * L2E) : (-L2E);
    const float mm  = isg ? (-4.0f * L2E) : 1.0f;
    const float aa  = isg ? ( 2.0f * L2E) : 0.0f;
    const bool gb0 = (g & 1) != 0;
    const bool gb1 = (g & 2) != 0;

    // per-chain recurrent weights; w*[k] multiplies h[(u-k)&15]
    float wf[16], wb[16];
    #pragma unroll
    for (int k = 0; k < 16; ++k) {
        const int m = (u - k) & 15;
        wf[k] = Whh_f[r * 16 + m] * sc;
        wb[k] = Whh_b[r * 16 + m] * sc;
        asm volatile("" : "+v"(wf[k]));
        asm volatile("" : "+v"(wb[k]));
    }
    const float wxf = Wih_f[r] * sc, wxb = Wih_b[r] * sc;
    const float bbf = b_f[r] * sc,  bbb = b_b[r] * sc;

    // replicated per-row state for both chains; c scaled by 2*log2e
    float hnF = h0[0 * (BATCH * HD) + b * HD + u];
    float ccF = c0[0 * (BATCH * HD) + b * HD + u] * (2.0f * L2E);
    float hnB = h0[1 * (BATCH * HD) + b * HD + u];
    float ccB = c0[1 * (BATCH * HD) + b * HD + u] * (2.0f * L2E);

    const float* srow = sent + b * TLEN;
    float* obF = g_outBT + (size_t)b * TLEN * HID + u;        // fwd half
    float* obB = g_outBT + (size_t)b * TLEN * HID + HD + u;   // bwd half

    // double-buffered x chunks for both ends (8 steps per chunk)
    float4 fA = *(const float4*)(srow + 0);
    float4 fB = *(const float4*)(srow + 4);
    float4 rA = *(const float4*)(srow + TLEN - 8);
    float4 rB = *(const float4*)(srow + TLEN - 4);
    for (int tb = 0; tb < TLEN; tb += 8) {
        float4 nfA = fA, nfB = fB, nrA = rA, nrB = rB;
        if (tb + 8 < TLEN) {
            nfA = *(const float4*)(srow + tb + 8);
            nfB = *(const float4*)(srow + tb + 12);
            nrA = *(const float4*)(srow + TLEN - 16 - tb);
            nrB = *(const float4*)(srow + TLEN - 12 - tb);
        }
        // chunk-order x: fwd ascending from tb; bwd descending from TLEN-1-tb
        const float xf[8] = {fA.x, fA.y, fA.z, fA.w, fB.x, fB.y, fB.z, fB.w};
        const float xb[8] = {rB.w, rB.z, rB.y, rB.x, rA.w, rA.z, rA.y, rA.x};
        // hoisted x-bases: off the serial chains
        float pbF[8], pbB[8];
        #pragma unroll
        for (int s2 = 0; s2 < 8; ++s2) {
            pbF[s2] = fmaf(xf[s2], wxf, bbf);
            pbB[s2] = fmaf(xb[s2], wxb, bbb);
        }

        float hsF[8], hsB[8];
        #pragma unroll
        for (int s2 = 0; s2 < 8; ++s2) {
            // two independent chains: scheduler interleaves, stalls overlap
            LSTM_STEP(hnF, ccF, wf, pbF[s2], hsF[s2])
            LSTM_STEP(hnB, ccB, wb, pbB[s2], hsB[s2])
        }

        // batched stores: g==0 rows, one exec toggle per 8 steps
        if (g == 0) {
            float* pF = obF + (size_t)tb * HID;
            float* pB = obB + (size_t)(TLEN - 1 - tb) * HID;
            #pragma unroll
            for (int s2 = 0; s2 < 8; ++s2) {
                pF[s2 * HID]    = hsF[s2];
                pB[-(s2 * HID)] = hsB[s2];
            }
        }
        fA = nfA; fB = nfB; rA = nrA; rB = nrB;
    }
}

// ---------------------------------------------------------------------------
// K2: projections. Thread per (b,t). W1 etc. staged in LDS.
// ---------------------------------------------------------------------------
__global__ __launch_bounds__(256) void k2_proj(
    const float* __restrict__ W1,     // [32,64]
    const float* __restrict__ b1,     // [32]
    const float* __restrict__ Wu,     // [32]
    const float* __restrict__ bu,     // [1]
    const float* __restrict__ Wout)   // [32]
{
    __shared__ float w1s[HID * 64];
    __shared__ float b1s[HID], wus[HID], wos[HID];
    const int tid = threadIdx.x;
    for (int k = tid; k < HID * 64; k += 256) w1s[k] = W1[k];
    if (tid < HID) { b1s[tid] = b1[tid]; wus[tid] = Wu[tid]; wos[tid] = Wout[tid]; }
    __syncthreads();

    const int g = blockIdx.x * 256 + tid;    // 0..8191
    const int b = g >> 9;
    const int t = g & (TLEN - 1);

    float o[32];
    const float4* src = (const float4*)(g_outBT + (size_t)g * HID);
    #pragma unroll
    for (int qq = 0; qq < 8; ++qq) {
        float4 v = src[qq];
        o[qq * 4 + 0] = v.x; o[qq * 4 + 1] = v.y; o[qq * 4 + 2] = v.z; o[qq * 4 + 3] = v.w;
    }

    float* pa = g_preA + (size_t)g * HID;
    float* ct = g_Ct + (size_t)b * HID * TLEN + t;
    #pragma unroll 4
    for (int h = 0; h < HID; ++h) {
        float a = b1s[h], cacc = 0.f;
        const float* wr = &w1s[h * 64];
        #pragma unroll
        for (int k = 0; k < HID; ++k) {
            a    = fmaf(o[k], wr[k], a);
            cacc = fmaf(o[k], wr[32 + k], cacc);
        }
        pa[h] = a;
        ct[(size_t)h * TLEN] = cacc;
    }

    float ua = 0.f, wa = 0.f;
    #pragma unroll
    for (int k = 0; k < HID; ++k) { ua = fmaf(o[k], wus[k], ua); wa = fmaf(o[k], wos[k], wa); }
    g_un[g]  = ua + bu[0];
    g_w2d[g] = wa;
}

// ---------------------------------------------------------------------------
// K34: S[b,i] = sum_j sum_h relu(preA[b,i,h] + Ct[b,h,j]) * W2[h]
//      prob[b,i] = sigmoid((S - diag_i + 511*b2)/100 + un[b,i])
//      out[b] = sum_i prob[b,i]*w2d[b,i] / 512 + bout
// ---------------------------------------------------------------------------
__global__ __launch_bounds__(256) void k34_binary(
    const float* __restrict__ W2,     // [32]
    const float* __restrict__ b2p,    // [1]
    const float* __restrict__ boutp,  // [1]
    float* __restrict__ out)          // [16]
{
    const int b     = blockIdx.x >> 6;
    const int itile = blockIdx.x & 63;
    const int i0    = itile * 8;
    const int tid   = threadIdx.x;

    __shared__ float pa[8][HID];
    __shared__ float w2s[HID];
    __shared__ float redw[4][8];

    pa[tid >> 5][tid & 31] = g_preA[((size_t)b * TLEN + i0 + (tid >> 5)) * HID + (tid & 31)];
    if (tid < HID) w2s[tid] = W2[tid];
    __syncthreads();

    const float* ctb = g_Ct + (size_t)b * HID * TLEN;
    const int j0 = tid, j1 = tid + 256;

    float acc[8];
    #pragma unroll
    for (int ii = 0; ii < 8; ++ii) acc[ii] = 0.f;

    #pragma unroll 8
    for (int h = 0; h < HID; ++h) {
        const float c0v = ctb[(size_t)h * TLEN + j0];
        const float c1v = ctb[(size_t)h * TLEN + j1];
        const float w   = w2s[h];
        #pragma unroll
        for (int ii = 0; ii < 8; ++ii) {
            const float p = pa[ii][h];
            acc[ii] = fmaf(fmaxf(p + c0v, 0.f), w, acc[ii]);
            acc[ii] = fmaf(fmaxf(p + c1v, 0.f), w, acc[ii]);
        }
    }

    #pragma unroll
    for (int ii = 0; ii < 8; ++ii) {
        float v = acc[ii];
        #pragma unroll
        for (int off = 32; off >= 1; off >>= 1) v += __shfl_down(v, off);
        if ((tid & 63) == 0) redw[tid >> 6][ii] = v;
    }
    __syncthreads();

    if (tid < 8) {
        const float S = redw[0][tid] + redw[1][tid] + redw[2][tid] + redw[3][tid];
        const int i = i0 + tid;
        float diag = 0.f;
        #pragma unroll
        for (int h = 0; h < HID; ++h)
            diag = fmaf(fmaxf(pa[tid][h] + ctb[(size_t)h * TLEN + i], 0.f), w2s[h], diag);
        const float b2 = b2p[0];
        const float s = (S - diag + (float)(TLEN - 1) * b2) * 0.01f + g_un[(size_t)b * TLEN + i];
        float contrib = sigm_(s) * g_w2d[(size_t)b * TLEN + i];
        contrib += __shfl_down(contrib, 4);
        contrib += __shfl_down(contrib, 2);
        contrib += __shfl_down(contrib, 1);
        if (tid == 0) {
            atomicAdd(&g_accum[b], contrib);
            __threadfence();
            int old = atomicAdd(&g_cnt[b], 1);
            if (old == 63) {
                __threadfence();
                float tot = atomicExch(&g_accum[b], 0.0f);
                out[b] = tot * (1.0f / (float)TLEN) + boutp[0];
                atomicExch(&g_cnt[b], 0);
            }
        }
    }
}

extern "C" void kernel_launch(void* const* d_in, const int* in_sizes, int n_in,
                              void* d_out, int out_size, void* d_ws, size_t ws_size,
                              hipStream_t stream) {
    const float* sent  = (const float*)d_in[0];
    const float* h0    = (const float*)d_in[1];
    const float* c0    = (const float*)d_in[2];
    const float* Wih_f = (const float*)d_in[3];
    const float* Whh_f = (const float*)d_in[4];
    const float* b_f   = (const float*)d_in[5];
    const float* Wih_b = (const float*)d_in[6];
    const float* Whh_b = (const float*)d_in[7];
    const float* b_b   = (const float*)d_in[8];
    const float* W1    = (const float*)d_in[9];
    const float* b1    = (const float*)d_in[10];
    const float* W2    = (const float*)d_in[11];
    const float* b2    = (const float*)d_in[12];
    const float* Wu    = (const float*)d_in[13];
    const float* bu    = (const float*)d_in[14];
    const float* Wout  = (const float*)d_in[15];
    const float* bout  = (const float*)d_in[16];

    k1_lstm<<<BATCH, 64, 0, stream>>>(sent, h0, c0, Wih_f, Whh_f, b_f,
                                      Wih_b, Whh_b, b_b);
    k2_proj<<<32, 256, 0, stream>>>(W1, b1, Wu, bu, Wout);
    k34_binary<<<1024, 256, 0, stream>>>(W2, b2, bout, (float*)d_out);
}

// Round 11
// 217.085 us; speedup vs baseline: 1.2708x; 1.2708x over previous
//
#include <hip/hip_runtime.h>
#include <hip/hip_bf16.h>
#include <math.h>

// Sizes (fixed by the problem)
#define BATCH 16
#define TLEN  512
#define HD    16     // per-direction hidden
#define HID   32     // 2*HD

typedef float v2f __attribute__((ext_vector_type(2)));
typedef unsigned u2v __attribute__((ext_vector_type(2)));

// ---------------------------------------------------------------------------
// Round 17: ALL scratch moved from __device__ globals into d_ws.
// Theory: the constant ~133 us non-k1 residual (invariant across 7 rounds) is
// the harness reset() train re-zeroing/restoring our 3 MB of __device__
// globals (dozens of tiny hipMemsetAsync dispatches, each ~2-5 us launch,
// inside the timed window). k2+k34 arithmetic is <=15 us. Carving scratch
// from d_ws removes those globals from the module image entirely.
// g_accum/g_cnt lose .bss zero-init -> k2 zeroes them (stream order puts k2
// strictly before k34). k1 reverted to the round-8 exact kernel (81.9 us,
// absmax 0) after round-10's two-chain merge spilled (VGPR=36 < working set).
//
// ws layout (floats):
//   outBT  [B*T*HID]   @ 0        (262144)
//   preA   [B*T*HID]   @ 262144   (262144)
//   Ct     [B*HID*T]   @ 524288   (262144)
//   un     [B*T]       @ 786432   (8192)
//   w2d    [B*T]       @ 794624   (8192)
//   accum  [B]         @ 802816   (16)
//   cnt    [B] (int)   @ 802832   (16)
// total 802848 floats = 3.06 MB <= ws_size (assumed).
// ---------------------------------------------------------------------------
#define WS_OUTBT 0
#define WS_PREA  262144
#define WS_CT    524288
#define WS_UN    786432
#define WS_W2D   794624
#define WS_ACC   802816
#define WS_CNT   802832

__device__ __forceinline__ float sigm_(float x) {
    return 1.0f / (1.0f + __expf(-x));
}

__device__ __forceinline__ float ex2_(float x) {
#if __has_builtin(__builtin_amdgcn_exp2f)
    return __builtin_amdgcn_exp2f(x);     // raw v_exp_f32 (2^x)
#else
    return exp2f(x);
#endif
}
__device__ __forceinline__ float rcp_(float x) {
#if __has_builtin(__builtin_amdgcn_rcpf)
    return __builtin_amdgcn_rcpf(x);      // raw v_rcp_f32 — avoids IEEE div chain
#else
    return 1.0f / x;
#endif
}

// ---------------------------------------------------------------------------
// K1: bidirectional LSTM — round-8 exact structure (measured 81.9 us).
// 1 chain/wave (32 blocks), lane r = gate row (g=r>>4, u=r&15), dir
// wave-uniform; folded exp2 scales; c scaled by 2*log2e; 8-step chunks;
// hoisted x-base; 4-accum dot; permlane gather + select ladder.
// ---------------------------------------------------------------------------
__global__ __launch_bounds__(64, 1) void k1_lstm(
    const float* __restrict__ sent,   // [B,T]
    const float* __restrict__ h0,     // [2,B,16]
    const float* __restrict__ c0,     // [2,B,16]
    const float* __restrict__ Wih_f, const float* __restrict__ Whh_f, const float* __restrict__ b_f,
    const float* __restrict__ Wih_b, const float* __restrict__ Whh_b, const float* __restrict__ b_b,
    float* __restrict__ ws)
{
    const int blk = blockIdx.x;       // 0..31
    const int dir = blk >> 4;         // 0 fwd, 1 bwd (wave-uniform)
    const int b   = blk & 15;         // batch
    const int r   = threadIdx.x;      // gate row 0..63
    const int u   = r & 15;           // unit
    const int g   = r >> 4;           // 0=i,1=f,2=g,3=o

    const float* Wih  = dir ? Wih_b : Wih_f;
    const float* Whh  = dir ? Whh_b : Whh_f;
    const float* bias = dir ? b_b   : b_f;

    const float L2E = 1.4426950408889634f;
    // fold the exp2 argument scale into this gate row's weights:
    //   sigm rows (i,f,o): p' = -log2e * p  -> sigm(p) = rcp(2^p' + 1)
    //   tanh row  (g):     p' = 2*log2e * p -> tanh(p) = 1 - 2*rcp(2^p' + 1)
    const bool  isg = (g == 2);
    const float sc  = isg ? (2.0f * L2E) : (-L2E);
    // act = fma(mm, rcp(2^p' + 1), aa); g row emits 2log2e*tanh directly.
    const float mm  = isg ? (-4.0f * L2E) : 1.0f;
    const float aa  = isg ? ( 2.0f * L2E) : 0.0f;

    // 16 scalar recurrent weights; wh<k> multiplies h[(u-k)&15].
    float wh0, wh1, wh2, wh3, wh4, wh5, wh6, wh7,
          wh8, wh9, wh10, wh11, wh12, wh13, wh14, wh15;
#define LDW(K) { const int m = (u - (K)) & 15; wh##K = Whh[r * 16 + m] * sc; }
    LDW(0)  LDW(1)  LDW(2)  LDW(3)  LDW(4)  LDW(5)  LDW(6)  LDW(7)
    LDW(8)  LDW(9)  LDW(10) LDW(11) LDW(12) LDW(13) LDW(14) LDW(15)
#undef LDW
    const float wx = Wih[r] * sc;
    const float bb = bias[r] * sc;

    const bool gb0 = (g & 1) != 0;
    const bool gb1 = (g & 2) != 0;

    // replicated per-row state: h[u], and c[u] scaled by 2*log2e
    float hn = h0[dir * (BATCH * HD) + b * HD + u];
    float cc = c0[dir * (BATCH * HD) + b * HD + u] * (2.0f * L2E);

    const float* srow = sent + b * TLEN;
    float* obase = ws + WS_OUTBT + (size_t)b * TLEN * HID + dir * HD + u;
    const int sg = dir ? -HID : HID;    // per-step store stride (elements)

    // 8-step chunks, double-buffered x (two float4 per chunk)
    float4 xcA = *(const float4*)(srow + (dir ? (TLEN - 8) : 0));
    float4 xcB = *(const float4*)(srow + (dir ? (TLEN - 4) : 4));
    for (int tb = 0; tb < TLEN; tb += 8) {
        float4 xnA = xcA, xnB = xcB;
        if (tb + 8 < TLEN) {
            const int nb = dir ? (TLEN - 16 - tb) : (tb + 8);
            xnA = *(const float4*)(srow + nb);
            xnB = *(const float4*)(srow + nb + 4);
        }
        // chunk-order x values (bwd consumes the chunk reversed)
        float xs[8];
        if (dir) {
            xs[0] = xcB.w; xs[1] = xcB.z; xs[2] = xcB.y; xs[3] = xcB.x;
            xs[4] = xcA.w; xs[5] = xcA.z; xs[6] = xcA.y; xs[7] = xcA.x;
        } else {
            xs[0] = xcA.x; xs[1] = xcA.y; xs[2] = xcA.z; xs[3] = xcA.w;
            xs[4] = xcB.x; xs[5] = xcB.y; xs[6] = xcB.z; xs[7] = xcB.w;
        }
        // hoisted x-base: independent of the recurrence, off the serial chain
        float pb[8];
        #pragma unroll
        for (int s2 = 0; s2 < 8; ++s2) pb[s2] = fmaf(xs[s2], wx, bb);

        float hsave[8];

        #pragma unroll
        for (int s2 = 0; s2 < 8; ++s2) {
            // 15 independent rotations of this row's h copy (literal DPP ctl)
            const int r0i = __float_as_int(hn);
            float rot[16];
            rot[0] = hn;
#define ROT(K) rot[K] = __int_as_float( \
                __builtin_amdgcn_mov_dpp(r0i, 0x120 + K, 0xF, 0xF, true));
            ROT(1)  ROT(2)  ROT(3)  ROT(4)  ROT(5)  ROT(6)  ROT(7)
            ROT(8)  ROT(9)  ROT(10) ROT(11) ROT(12) ROT(13) ROT(14) ROT(15)
#undef ROT

            // 16-term scalar dot, 4 accumulators (dep depth 4 + 2 add levels)
            float a0 = fmaf(rot[0], wh0,  pb[s2]);
            float a1 = rot[1] * wh1;
            float a2 = rot[2] * wh2;
            float a3 = rot[3] * wh3;
            a0 = fmaf(rot[4],  wh4,  a0);
            a1 = fmaf(rot[5],  wh5,  a1);
            a2 = fmaf(rot[6],  wh6,  a2);
            a3 = fmaf(rot[7],  wh7,  a3);
            a0 = fmaf(rot[8],  wh8,  a0);
            a1 = fmaf(rot[9],  wh9,  a1);
            a2 = fmaf(rot[10], wh10, a2);
            a3 = fmaf(rot[11], wh11, a3);
            a0 = fmaf(rot[12], wh12, a0);
            a1 = fmaf(rot[13], wh13, a1);
            a2 = fmaf(rot[14], wh14, a2);
            a3 = fmaf(rot[15], wh15, a3);
            const float p = (a0 + a1) + (a2 + a3);   // pre-act, scale folded

            // activation: act = fma(mm, rcp(2^p + 1), aa)
            const float e   = ex2_(p);
            const float iv  = rcp_(e + 1.0f);
            const float act = fmaf(mm, iv, aa);
            // i/f/o rows: sigm(p).  g row: 2log2e * tanh(p).

            // gather the other three gate rows' activations (VALU permlane)
            float x1, x2, x3;
            {
                const unsigned ai_ = (unsigned)__float_as_int(act);
                u2v q16 = __builtin_amdgcn_permlane16_swap(ai_, ai_, false, false);
                x1 = __int_as_float((int)(gb0 ? q16[0] : q16[1]));
                u2v q32 = __builtin_amdgcn_permlane32_swap(ai_, ai_, false, false);
                const unsigned x2i = gb1 ? q32[0] : q32[1];
                x2 = __int_as_float((int)x2i);
                u2v q48 = __builtin_amdgcn_permlane16_swap(x2i, x2i, false, false);
                x3 = __int_as_float((int)(gb0 ? q48[0] : q48[1]));
            }

            // X[s] = act of row g^s; role j needs X[g^j]  (round-10 verified)
            const float lo_i = gb0 ? x1  : act;
            const float hi_i = gb0 ? x3  : x2;
            const float ai   = gb1 ? hi_i : lo_i;     // X[g]   = sigm_i
            const float lo_f = gb0 ? act : x1;
            const float hi_f = gb0 ? x2  : x3;
            const float af   = gb1 ? hi_f : lo_f;     // X[g^1] = sigm_f
            const float lo_g = gb0 ? x1  : act;
            const float hi_g = gb0 ? x3  : x2;
            const float ag   = gb1 ? lo_g : hi_g;     // X[g^2] = 2log2e*tanh_g
            const float lo_o = gb0 ? act : x1;
            const float hi_o = gb0 ? x2  : x3;
            const float ao   = gb1 ? lo_o : hi_o;     // X[g^3] = sigm_o

            // c' = af*c' + ai*(2log2e*tanh_g)   (c' = 2log2e * c)
            cc = fmaf(af, cc, ai * ag);
            // tanh(c) = 1 - 2*rcp(2^c' + 1)  (overflow-safe: E=inf -> z=1)
            const float e2   = ex2_(cc);
            const float inv2 = rcp_(e2 + 1.0f);
            const float z    = fmaf(-2.0f, inv2, 1.0f);
            hn = ao * z;
            hsave[s2] = hn;
        }

        // batched store: g==0 rows (16 lanes), one exec toggle per 8 steps
        if (g == 0) {
            float* bp = obase + (size_t)(dir ? (TLEN - 1 - tb) : tb) * HID;
            #pragma unroll
            for (int s2 = 0; s2 < 8; ++s2) bp[s2 * sg] = hsave[s2];
        }
        xcA = xnA; xcB = xnB;
    }
}

// ---------------------------------------------------------------------------
// K2: projections. Thread per (b,t). W1 etc. staged in LDS.
// Also zeroes accum/cnt (k34 is stream-ordered after k2, so this is safe and
// replaces the lost .bss zero-init).
// ---------------------------------------------------------------------------
__global__ __launch_bounds__(256) void k2_proj(
    const float* __restrict__ W1,     // [32,64]
    const float* __restrict__ b1,     // [32]
    const float* __restrict__ Wu,     // [32]
    const float* __restrict__ bu,     // [1]
    const float* __restrict__ Wout,   // [32]
    float* __restrict__ ws)
{
    __shared__ float w1s[HID * 64];
    __shared__ float b1s[HID], wus[HID], wos[HID];
    const int tid = threadIdx.x;
    for (int k = tid; k < HID * 64; k += 256) w1s[k] = W1[k];
    if (tid < HID) { b1s[tid] = b1[tid]; wus[tid] = Wu[tid]; wos[tid] = Wout[tid]; }
    if (blockIdx.x == 0 && tid < BATCH) {
        ws[WS_ACC + tid] = 0.0f;
        ((int*)(ws + WS_CNT))[tid] = 0;
    }
    __syncthreads();

    const int g = blockIdx.x * 256 + tid;    // 0..8191
    const int b = g >> 9;
    const int t = g & (TLEN - 1);

    float o[32];
    const float4* src = (const float4*)(ws + WS_OUTBT + (size_t)g * HID);
    #pragma unroll
    for (int qq = 0; qq < 8; ++qq) {
        float4 v = src[qq];
        o[qq * 4 + 0] = v.x; o[qq * 4 + 1] = v.y; o[qq * 4 + 2] = v.z; o[qq * 4 + 3] = v.w;
    }

    float* pa = ws + WS_PREA + (size_t)g * HID;
    float* ct = ws + WS_CT + (size_t)b * HID * TLEN + t;
    #pragma unroll 4
    for (int h = 0; h < HID; ++h) {
        float a = b1s[h], cacc = 0.f;
        const float* wr = &w1s[h * 64];
        #pragma unroll
        for (int k = 0; k < HID; ++k) {
            a    = fmaf(o[k], wr[k], a);
            cacc = fmaf(o[k], wr[32 + k], cacc);
        }
        pa[h] = a;
        ct[(size_t)h * TLEN] = cacc;
    }

    float ua = 0.f, wa = 0.f;
    #pragma unroll
    for (int k = 0; k < HID; ++k) { ua = fmaf(o[k], wus[k], ua); wa = fmaf(o[k], wos[k], wa); }
    ws[WS_UN + g]  = ua + bu[0];
    ws[WS_W2D + g] = wa;
}

// ---------------------------------------------------------------------------
// K34: S[b,i] = sum_j sum_h relu(preA[b,i,h] + Ct[b,h,j]) * W2[h]
//      prob[b,i] = sigmoid((S - diag_i + 511*b2)/100 + un[b,i])
//      out[b] = sum_i prob[b,i]*w2d[b,i] / 512 + bout
// ---------------------------------------------------------------------------
__global__ __launch_bounds__(256) void k34_binary(
    const float* __restrict__ W2,     // [32]
    const float* __restrict__ b2p,    // [1]
    const float* __restrict__ boutp,  // [1]
    float* __restrict__ out,          // [16]
    float* __restrict__ ws)
{
    const int b     = blockIdx.x >> 6;
    const int itile = blockIdx.x & 63;
    const int i0    = itile * 8;
    const int tid   = threadIdx.x;

    __shared__ float pa[8][HID];
    __shared__ float w2s[HID];
    __shared__ float redw[4][8];

    pa[tid >> 5][tid & 31] =
        ws[WS_PREA + ((size_t)b * TLEN + i0 + (tid >> 5)) * HID + (tid & 31)];
    if (tid < HID) w2s[tid] = W2[tid];
    __syncthreads();

    const float* ctb = ws + WS_CT + (size_t)b * HID * TLEN;
    const int j0 = tid, j1 = tid + 256;

    float acc[8];
    #pragma unroll
    for (int ii = 0; ii < 8; ++ii) acc[ii] = 0.f;

    #pragma unroll 8
    for (int h = 0; h < HID; ++h) {
        const float c0v = ctb[(size_t)h * TLEN + j0];
        const float c1v = ctb[(size_t)h * TLEN + j1];
        const float w   = w2s[h];
        #pragma unroll
        for (int ii = 0; ii < 8; ++ii) {
            const float p = pa[ii][h];
            acc[ii] = fmaf(fmaxf(p + c0v, 0.f), w, acc[ii]);
            acc[ii] = fmaf(fmaxf(p + c1v, 0.f), w, acc[ii]);
        }
    }

    #pragma unroll
    for (int ii = 0; ii < 8; ++ii) {
        float v = acc[ii];
        #pragma unroll
        for (int off = 32; off >= 1; off >>= 1) v += __shfl_down(v, off);
        if ((tid & 63) == 0) redw[tid >> 6][ii] = v;
    }
    __syncthreads();

    if (tid < 8) {
        const float S = redw[0][tid] + redw[1][tid] + redw[2][tid] + redw[3][tid];
        const int i = i0 + tid;
        float diag = 0.f;
        #pragma unroll
        for (int h = 0; h < HID; ++h)
            diag = fmaf(fmaxf(pa[tid][h] + ctb[(size_t)h * TLEN + i], 0.f), w2s[h], diag);
        const float b2 = b2p[0];
        const float s = (S - diag + (float)(TLEN - 1) * b2) * 0.01f
                        + ws[WS_UN + (size_t)b * TLEN + i];
        float contrib = sigm_(s) * ws[WS_W2D + (size_t)b * TLEN + i];
        contrib += __shfl_down(contrib, 4);
        contrib += __shfl_down(contrib, 2);
        contrib += __shfl_down(contrib, 1);
        if (tid == 0) {
            float* accum = ws + WS_ACC;
            int*   cnt   = (int*)(ws + WS_CNT);
            atomicAdd(&accum[b], contrib);
            __threadfence();
            int old = atomicAdd(&cnt[b], 1);
            if (old == 63) {                          // last arriver for this b
                __threadfence();
                float tot = accum[b];
                out[b] = tot * (1.0f / (float)TLEN) + boutp[0];
            }
        }
    }
}

extern "C" void kernel_launch(void* const* d_in, const int* in_sizes, int n_in,
                              void* d_out, int out_size, void* d_ws, size_t ws_size,
                              hipStream_t stream) {
    const float* sent  = (const float*)d_in[0];
    const float* h0    = (const float*)d_in[1];
    const float* c0    = (const float*)d_in[2];
    const float* Wih_f = (const float*)d_in[3];
    const float* Whh_f = (const float*)d_in[4];
    const float* b_f   = (const float*)d_in[5];
    const float* Wih_b = (const float*)d_in[6];
    const float* Whh_b = (const float*)d_in[7];
    const float* b_b   = (const float*)d_in[8];
    const float* W1    = (const float*)d_in[9];
    const float* b1    = (const float*)d_in[10];
    const float* W2    = (const float*)d_in[11];
    const float* b2    = (const float*)d_in[12];
    const float* Wu    = (const float*)d_in[13];
    const float* bu    = (const float*)d_in[14];
    const float* Wout  = (const float*)d_in[15];
    const float* bout  = (const float*)d_in[16];

    float* ws = (float*)d_ws;

    k1_lstm<<<32, 64, 0, stream>>>(sent, h0, c0, Wih_f, Whh_f, b_f,
                                   Wih_b, Whh_b, b_b, ws);
    k2_proj<<<32, 256, 0, stream>>>(W1, b1, Wu, bu, Wout, ws);
    k34_binary<<<1024, 256, 0, stream>>>(W2, b2, bout, (float*)d_out, ws);
}